// Round 1
// baseline (477.523 us; speedup 1.0000x reference)
//
#include <hip/hip_runtime.h>

#define N_NODES_C  100000
#define N_EDGES_C  1600000
#define IN_FEATS_C 128
#define OUT_FEATS_C 32
#define NEG_SLOPE_C 0.2f

// Static device scratch (≈14 MB): avoids any assumption about ws_size.
__device__ float g_z[N_NODES_C * OUT_FEATS_C];
__device__ float g_el[N_NODES_C];
__device__ float g_er[N_NODES_C];
__device__ float g_denom[N_NODES_C];

// Kernel 1: z = h @ W.T ; el = z . a_l ; er = z . a_r ; denom = 0
// Half-wave (32 lanes) per node, lane = out-feature.
// h row reads are lane-broadcast (same addr across the 32-lane group);
// W (16 KB) is L1-resident after first touch.
__global__ __launch_bounds__(256) void k_project(const float* __restrict__ h,
                                                 const float* __restrict__ W,
                                                 const float* __restrict__ a,
                                                 int n_nodes)
{
    int tid  = blockIdx.x * blockDim.x + threadIdx.x;
    int node = tid >> 5;
    int f    = tid & 31;
    if (node >= n_nodes) return;

    const float4* h4 = (const float4*)(h + (size_t)node * IN_FEATS_C);
    const float4* w4 = (const float4*)(W + (size_t)f * IN_FEATS_C);
    float acc = 0.f;
#pragma unroll 8
    for (int k = 0; k < IN_FEATS_C / 4; ++k) {
        float4 hv = h4[k];
        float4 wv = w4[k];
        acc += hv.x * wv.x;
        acc += hv.y * wv.y;
        acc += hv.z * wv.z;
        acc += hv.w * wv.w;
    }
    g_z[(size_t)node * OUT_FEATS_C + f] = acc;

    // el/er: reduce acc*a over the 32 lanes of this half-wave.
    float zl = acc * a[f];
    float zr = acc * a[OUT_FEATS_C + f];
#pragma unroll
    for (int m = 16; m >= 1; m >>= 1) {
        zl += __shfl_xor(zl, m, 64);
        zr += __shfl_xor(zr, m, 64);
    }
    if (f == 0) { g_el[node] = zl; g_er[node] = zr; }
    if (f == 1) g_denom[node] = 0.f;
}

// Kernel 2: one half-wave per edge, lane = feature.
// e = leaky_relu(el[src] + er[dst]); ex = exp(e)  (softmax shift dropped —
// shift-invariant, logits are O(5) so exp is safe in f32).
// out[dst,:] += ex * z[src,:]  (coalesced 128B atomic segment)
// denom[dst] += ex             (lane 0 only)
__global__ __launch_bounds__(256) void k_edge(const int* __restrict__ src,
                                              const int* __restrict__ dst,
                                              float* __restrict__ out,
                                              int n_edges)
{
    int tid = blockIdx.x * blockDim.x + threadIdx.x;
    int e   = tid >> 5;
    int f   = tid & 31;
    if (e >= n_edges) return;

    int s = src[e];
    int d = dst[e];
    float x = g_el[s] + g_er[d];
    x = (x > 0.f) ? x : NEG_SLOPE_C * x;
    float ex = expf(x);

    if (f == 0) atomicAdd(&g_denom[d], ex);
    atomicAdd(&out[(size_t)d * OUT_FEATS_C + f],
              ex * g_z[(size_t)s * OUT_FEATS_C + f]);
}

// Kernel 3: out /= max(denom, 1e-16), float4-vectorized.
// Each float4 covers 4 feats of one node (32 feats/node, 8 float4s/node).
__global__ __launch_bounds__(256) void k_norm(float* __restrict__ out, int n4)
{
    int i = blockIdx.x * blockDim.x + threadIdx.x;
    if (i >= n4) return;
    int node = i >> 3;
    float dn = fmaxf(g_denom[node], 1e-16f);
    float inv = 1.0f / dn;
    float4 v = ((float4*)out)[i];
    v.x *= inv; v.y *= inv; v.z *= inv; v.w *= inv;
    ((float4*)out)[i] = v;
}

extern "C" void kernel_launch(void* const* d_in, const int* in_sizes, int n_in,
                              void* d_out, int out_size, void* d_ws, size_t ws_size,
                              hipStream_t stream) {
    const float* h   = (const float*)d_in[0];
    const float* W   = (const float*)d_in[1];
    const float* a   = (const float*)d_in[2];
    const int*   src = (const int*)d_in[3];
    const int*   dst = (const int*)d_in[4];
    float* out = (float*)d_out;

    const int n_nodes = in_sizes[0] / IN_FEATS_C;   // 100000
    const int n_edges = in_sizes[3];                // 1600000

    // Zero the output accumulator (harness poisons it; we accumulate into it).
    hipMemsetAsync(d_out, 0, (size_t)out_size * sizeof(float), stream);

    {   // projection: 32 threads per node
        int total = n_nodes * 32;
        int blocks = (total + 255) / 256;
        k_project<<<blocks, 256, 0, stream>>>(h, W, a, n_nodes);
    }
    {   // edge scatter: 32 threads per edge
        long long total = (long long)n_edges * 32;
        int blocks = (int)((total + 255) / 256);
        k_edge<<<blocks, 256, 0, stream>>>(src, dst, out, n_edges);
    }
    {   // normalize: float4 per thread
        int n4 = (n_nodes * OUT_FEATS_C) / 4;
        int blocks = (n4 + 255) / 256;
        k_norm<<<blocks, 256, 0, stream>>>(out, n4);
    }
}